// Round 7
// baseline (269.076 us; speedup 1.0000x reference)
//
#include <hip/hip_runtime.h>
#include <hip/hip_bf16.h>
#include <cstdint>

// ---------------------------------------------------------------------------
// SingleHeadAttentionLayer: B=4, S=2048, D=KD=VD=1024, fp32 in/out.
// Round 15: 8-phase 256^2 core, CORRECTED after R6 fail (absmax 3.14):
//  BUG1: fragment reads spanned both stage-halves (R = wm*128+ihalf*64+..)
//        -> P2's stage of half A0 overwrote rows 64..127 still needed by
//        P3's ldsA(.,1). FIX: align read-half with stage-half:
//        row = ihalf*128 + wm*64 + i2*16 + l16,
//        col = jhalf*128 + wn*32 + j2*16 + l16  (wave owns 2x64-row strips
//        x 2x32-col strips = 128x64; acc[8][4] unchanged).
//  BUG2: pvo nT was 2*(mb+1) K64-tiles = half the causal extent.
//        FIX: nT = 4*(mb+1).
// Ledger (re-traced with fixed mapping): per K-tile pair (T buf0, T+1 buf1):
//   P1 rd A0,B0  st (T+1).B0 | P2 rd B1 st (T+2).A0 | P3 rd A1 st (T+2).B1
//   P4 rd B0     st (T+2).A1 + vmcnt(6)  [T+1 fully landed]
//   P5 rd A0,B0  st (T+2).B0 | P6 rd B1 st (T+3).A0 | P7 rd A1 st (T+3).B1
//   P8 rd B0     st (T+3).A1 + vmcnt(6)  [T+2 fully landed]
// Each stage's target region was last read in the PREVIOUS phase (phase-end
// barrier + per-wave lgkmcnt(0) => collective). vmcnt(6) is per-wave but
// followed by barrier => collective RAW cover. Tail clamps idempotent.
// Phase = {ds_read frags || stage half-tile} -> [vm6] -> bar -> lgkmcnt(0)
// -> sched_barrier -> setprio(1) 16 MFMA setprio(0) -> bar.   (T2+T3+T4+T5)
// Pipeline:
//   prep2b:  weight casts/transposes, bvo, c, lsum=0, x cast  (11010 blk)
//   gemmW:   Mt(16) + Wvo(16) @256^2 + m1/m2 GEMVs(32)        (64 blk @512)
//   big1:    y2(128) + Ut(128) @256^2 + u GEMV(128)           (384 blk @512)
//   scoresP: P = exp(|y2.x^T+u|/32) causal + rowsums          (144 blk @512)
//   pvo:     out = (P@U)/l + bo, causal-K                     (128 blk @512)
// ---------------------------------------------------------------------------

typedef __attribute__((ext_vector_type(8))) __bf16 bf16x8;
typedef __attribute__((ext_vector_type(4))) __bf16 bf16x4;
typedef __attribute__((ext_vector_type(4))) float floatx4;

struct Ptr3 { const float* p[3]; };

__device__ __forceinline__ void async_copy16(const __bf16* g, const __bf16* l) {
  __builtin_amdgcn_global_load_lds(
      (const __attribute__((address_space(1))) unsigned int*)(const void*)g,
      (__attribute__((address_space(3))) unsigned int*)(unsigned)(uintptr_t)(const void*)l,
      16, 0, 0);
}

// ---------------- 8-phase 256x256 core, K-tiles of 64, nT EVEN --------------
// ONE call site per kernel (128 KB LDS). 512 threads.
__device__ __forceinline__ void gemm_core8p(const __bf16* __restrict__ pA,
                                            const __bf16* __restrict__ pB,
                                            int K, int nT, int mb, int nb,
                                            floatx4 (&acc)[8][4]) {
  __shared__ __align__(16) __bf16 As[2][16384];
  __shared__ __align__(16) __bf16 Bs[2][16384];

  const int t = threadIdx.x;           // 0..511
  const int lane = t & 63;
  const int wave = t >> 6;             // 0..7
  const int quad = lane >> 4;          // 0..3
  const int l16 = lane & 15;
  const int wm = wave >> 2;            // 0..1 -> row strip wm*64 in each half
  const int wn = wave & 3;             // 0..3 -> col strip wn*32 in each half

  // Stage addressing (rule #21): thread t covers local rows r0=t>>3 and
  // r0+64 of a 128-row half-tile, source chunk (t&7)^(r0&7).
  const int r0 = t >> 3;
  const int csw = ((t & 7) ^ (r0 & 7)) * 8;
  const __bf16* gA = pA + (long)(mb * 256 + r0) * K + csw;
  const __bf16* gB = pB + (long)(nb * 256 + r0) * K + csw;
  const long row64 = (long)64 * K;
  const long row128 = (long)128 * K;

  auto stageA = [&](int kt, int half) {
    const long ko = (long)kt * 64 + (long)half * row128;
    __bf16* d = &As[kt & 1][half * 8192 + t * 8];
    async_copy16(gA + ko, d);
    async_copy16(gA + ko + row64, d + 4096);
  };
  auto stageB = [&](int kt, int half) {
    const long ko = (long)kt * 64 + (long)half * row128;
    __bf16* d = &Bs[kt & 1][half * 8192 + t * 8];
    async_copy16(gB + ko, d);
    async_copy16(gB + ko + row64, d + 4096);
  };
  auto cl = [&](int kt) { return kt < nT ? kt : nT - 1; };

  bf16x8 af[4][2], bfr[2][2];
  // ldsA(buf, ihalf) reads ONLY rows [ihalf*128, ihalf*128+128) == stage
  // half `ihalf` (the R6 bug fix).
  auto ldsA = [&](int buf, int ihalf) {
#pragma unroll
    for (int i2 = 0; i2 < 4; ++i2) {
      const int rl = wm * 64 + i2 * 16 + l16;        // 0..127 within half
      const int rb = ihalf * 8192 + rl * 64;
      const int key = rl & 7;
#pragma unroll
      for (int ks = 0; ks < 2; ++ks)
        af[i2][ks] = *(const bf16x8*)&As[buf][rb + (((ks * 4 + quad) ^ key) << 3)];
    }
  };
  auto ldsB = [&](int buf, int jhalf) {
#pragma unroll
    for (int j2 = 0; j2 < 2; ++j2) {
      const int rl = wn * 32 + j2 * 16 + l16;        // 0..127 within half
      const int rb = jhalf * 8192 + rl * 64;
      const int key = rl & 7;
#pragma unroll
      for (int ks = 0; ks < 2; ++ks)
        bfr[j2][ks] = *(const bf16x8*)&Bs[buf][rb + (((ks * 4 + quad) ^ key) << 3)];
    }
  };
  auto mfmaQ = [&](int ihalf, int jhalf) {
    __builtin_amdgcn_s_setprio(1);
#pragma unroll
    for (int ks = 0; ks < 2; ++ks)
#pragma unroll
      for (int i2 = 0; i2 < 4; ++i2)
#pragma unroll
        for (int j2 = 0; j2 < 2; ++j2)
          acc[ihalf * 4 + i2][jhalf * 2 + j2] =
              __builtin_amdgcn_mfma_f32_16x16x32_bf16(
                  af[i2][ks], bfr[j2][ks],
                  acc[ihalf * 4 + i2][jhalf * 2 + j2], 0, 0, 0);
    __builtin_amdgcn_s_setprio(0);
  };

#define VM6 asm volatile("s_waitcnt vmcnt(6)" ::: "memory")
#define PHASE(LDSOP, STAGEOP, WAITOP, IH, JH)                 \
  LDSOP;                                                      \
  STAGEOP;                                                    \
  WAITOP;                                                     \
  __builtin_amdgcn_sched_barrier(0);                          \
  __builtin_amdgcn_s_barrier();                               \
  asm volatile("s_waitcnt lgkmcnt(0)" ::: "memory");          \
  __builtin_amdgcn_sched_barrier(0);                          \
  mfmaQ(IH, JH);                                              \
  __builtin_amdgcn_s_barrier();

  // Prologue: 7 half-tiles (T0 complete, T1 minus B0), FIFO oldest = T0.
  stageA(0, 0); stageB(0, 0); stageB(0, 1); stageA(0, 1);
  stageA(1, 0); stageB(1, 1); stageA(1, 1);
  VM6;                                   // own T0 loads landed
  __builtin_amdgcn_s_barrier();          // -> all waves' T0 loads landed
  __builtin_amdgcn_sched_barrier(0);

  const int nIter = nT >> 1;
  for (int it = 0, T = 0; it < nIter; ++it, T += 2) {
    // tile T (buf0)
    PHASE((ldsA(0, 0), ldsB(0, 0)), stageB(cl(T + 1), 0), (void)0, 0, 0)
    PHASE(ldsB(0, 1),               stageA(cl(T + 2), 0), (void)0, 0, 1)
    PHASE(ldsA(0, 1),               stageB(cl(T + 2), 1), (void)0, 1, 1)
    PHASE(ldsB(0, 0),               stageA(cl(T + 2), 1), VM6,     1, 0)
    // tile T+1 (buf1)
    PHASE((ldsA(1, 0), ldsB(1, 0)), stageB(cl(T + 2), 0), (void)0, 0, 0)
    PHASE(ldsB(1, 1),               stageA(cl(T + 3), 0), (void)0, 0, 1)
    PHASE(ldsA(1, 1),               stageB(cl(T + 3), 1), (void)0, 1, 1)
    PHASE(ldsB(1, 0),               stageA(cl(T + 3), 1), VM6,     1, 0)
  }
  __syncthreads();  // drain leftover clamped prefetches
#undef PHASE
#undef VM6
}

// Epilogue index helpers for the fixed mapping:
//   row(i, r) = (i>>2)*128 + wm*64 + (i&3)*16 + quad*4 + r
//   col(j)    = (j>>1)*128 + wn*32 + (j&1)*16 + l16

// ---------------- prep2b: weight prep + x cast ------------------------------
__global__ void prep2b(const float* __restrict__ Wo, Ptr3 tp,
                       const float* __restrict__ bv, const float* __restrict__ bq,
                       const float* __restrict__ bk, const float* __restrict__ x,
                       __bf16* __restrict__ Wob, __bf16* __restrict__ Wqt,
                       __bf16* __restrict__ Wkt, __bf16* __restrict__ Wvt,
                       __bf16* __restrict__ xb, float* __restrict__ bvo,
                       float* __restrict__ cscal, float* __restrict__ lsum) {
  __shared__ __bf16 tile[64][66];
  __shared__ float wsum[4];
  const int bid = blockIdx.x;
  const int t = threadIdx.x;
  if (bid >= 2818) {  // x cast
    const long i = ((long)(bid - 2818) * 256 + t) * 4;
    const float4 f = *(const float4*)(x + i);
    bf16x4 o;
    o[0] = (__bf16)f.x; o[1] = (__bf16)f.y; o[2] = (__bf16)f.z; o[3] = (__bf16)f.w;
    *(bf16x4*)(xb + i) = o;
  } else if (bid < 1024) {  // Wo cast
    const long e = ((long)bid * 256 + t) * 4;
    const float4 f = *(const float4*)(Wo + e);
    bf16x4 o;
    o[0] = (__bf16)f.x; o[1] = (__bf16)f.y; o[2] = (__bf16)f.z; o[3] = (__bf16)f.w;
    *(bf16x4*)(Wob + e) = o;
  } else if (bid < 1792) {  // transposed casts
    const int seg = (bid - 1024) >> 8;
    const int idx = (bid - 1024) & 255;
    const float* src = tp.p[seg];
    __bf16* dstw = seg == 0 ? Wqt : (seg == 1 ? Wkt : Wvt);
    const int r0 = (idx >> 4) * 64, c0 = (idx & 15) * 64;
#pragma unroll
    for (int e = 0; e < 16; ++e) {
      const int i = e * 256 + t;
      const int r = i >> 6, c = i & 63;
      tile[r][c] = (__bf16)src[(long)(r0 + r) * 1024 + (c0 + c)];
    }
    __syncthreads();
#pragma unroll
    for (int e = 0; e < 16; ++e) {
      const int i = e * 256 + t;
      const int r = i >> 6, c = i & 63;
      dstw[(long)(c0 + r) * 1024 + (r0 + c)] = tile[c][r];
    }
  } else if (bid < 2816) {  // bvo
    const int d = bid - 1792;
    const float* row = Wo + (long)d * 1024;
    float s = 0.f;
    for (int v = t; v < 1024; v += 256) s += bv[v] * row[v];
#pragma unroll
    for (int off = 32; off > 0; off >>= 1) s += __shfl_down(s, off, 64);
    if ((t & 63) == 0) wsum[t >> 6] = s;
    __syncthreads();
    if (t == 0) bvo[d] = wsum[0] + wsum[1] + wsum[2] + wsum[3];
  } else if (bid == 2816) {  // c = bq . bk
    float s = 0.f;
    for (int i = t; i < 1024; i += 256) s += bq[i] * bk[i];
#pragma unroll
    for (int off = 32; off > 0; off >>= 1) s += __shfl_down(s, off, 64);
    if ((t & 63) == 0) wsum[t >> 6] = s;
    __syncthreads();
    if (t == 0) *cscal = wsum[0] + wsum[1] + wsum[2] + wsum[3];
  } else {  // zero lsum
#pragma unroll
    for (int e = 0; e < 8; ++e)
      *(float4*)(lsum + (e * 256 + t) * 4) = float4{0.f, 0.f, 0.f, 0.f};
  }
}

// ---------------- gemmW: Mt(16) + Wvo(16) @256^2 + m1/m2 GEMVs(32) ----------
__global__ void __launch_bounds__(512, 2)
gemmW(const __bf16* __restrict__ Wkt, const __bf16* __restrict__ Wqt,
      const __bf16* __restrict__ Wob, const __bf16* __restrict__ Wvt,
      __bf16* __restrict__ Mt, __bf16* __restrict__ Wvo,
      const float* __restrict__ bk, const float* __restrict__ bq,
      float* __restrict__ m1f, float* __restrict__ m2f) {
  const int id = blockIdx.x;
  const int t = threadIdx.x;

  if (id >= 32) {  // m1[row]=Wqt[row,:].bk / m2[row]=Wkt[row,:].bq
    const int g = id - 32;
    const bool isM2 = g >= 16;
    const int q = g & 15;
    const __bf16* Wt = isM2 ? Wkt : Wqt;
    const float* bvec = isM2 ? bq : bk;
    float* dst = isM2 ? m2f : m1f;
    const int row = q * 64 + (t >> 3);
    const int l8 = t & 7;
    const __bf16* wr = Wt + (long)row * 1024 + l8 * 128;
    const float* bp = bvec + l8 * 128;
    float s = 0.f;
#pragma unroll
    for (int jj = 0; jj < 16; ++jj) {
      bf16x8 wv = *(const bf16x8*)(wr + jj * 8);
#pragma unroll
      for (int e = 0; e < 8; ++e) s += (float)wv[e] * bp[jj * 8 + e];
    }
    s += __shfl_xor(s, 1, 64);
    s += __shfl_xor(s, 2, 64);
    s += __shfl_xor(s, 4, 64);
    if (l8 == 0) dst[row] = s;
    return;
  }

  const bool isMt = id < 16;
  const int w = isMt ? id : id - 16;
  const int mb = w >> 2, nb = w & 3;
  const __bf16* pA = isMt ? Wkt : Wob;
  const __bf16* pB = isMt ? Wqt : Wvt;
  __bf16* dst = isMt ? Mt : Wvo;

  floatx4 acc[8][4] = {};
  gemm_core8p(pA, pB, 1024, 16, mb, nb, acc);

  const int lane = t & 63, wave = t >> 6;
  const int quad = lane >> 4, l16 = lane & 15;
  const int wm = wave >> 2, wn = wave & 3;
#pragma unroll
  for (int j = 0; j < 4; ++j) {
    const int gc = nb * 256 + (j >> 1) * 128 + wn * 32 + (j & 1) * 16 + l16;
#pragma unroll
    for (int i = 0; i < 8; ++i) {
      const int gr = mb * 256 + (i >> 2) * 128 + wm * 64 + (i & 3) * 16 + quad * 4;
#pragma unroll
      for (int r = 0; r < 4; ++r)
        dst[(long)(gr + r) * 1024 + gc] = (__bf16)acc[i][j][r];
    }
  }
}

// ---------------- big1: y2(128) + Ut(128) @256^2 + u GEMV(128) --------------
__global__ void __launch_bounds__(512, 2)
big1(const __bf16* __restrict__ xb, const __bf16* __restrict__ Mt,
     const __bf16* __restrict__ Wvo, const float* __restrict__ m2f,
     const float* __restrict__ bvo, __bf16* __restrict__ y2,
     __bf16* __restrict__ Ut, const float* __restrict__ m1f,
     const float* __restrict__ cscal, float* __restrict__ uvec,
     int S, int D) {
  const int id = blockIdx.x;
  const int t = threadIdx.x;

  if (id >= 256) {  // u rows: 128 blocks x 64 rows, 8 threads/row
    const int k = id - 256;
    const int row = k * 64 + (t >> 3);
    const int l8 = t & 7;
    const float c = *cscal;
    const __bf16* xr = xb + (long)row * 1024 + l8 * 128;
    const float* mp = m1f + l8 * 128;
    float s = 0.f;
#pragma unroll
    for (int jj = 0; jj < 16; ++jj) {
      bf16x8 xv = *(const bf16x8*)(xr + jj * 8);
#pragma unroll
      for (int e = 0; e < 8; ++e) s += (float)xv[e] * mp[jj * 8 + e];
    }
    s += __shfl_xor(s, 1, 64);
    s += __shfl_xor(s, 2, 64);
    s += __shfl_xor(s, 4, 64);
    if (l8 == 0) uvec[row] = s + c;
    return;
  }

  const bool isY2 = id < 128;
  const int w = isY2 ? id : id - 128;
  const int mb = w >> 2;   // 0..31
  const int nb = w & 3;    // 0..3
  const __bf16* pB = isY2 ? Mt : Wvo;

  floatx4 acc[8][4] = {};
  gemm_core8p(xb, pB, 1024, 16, mb, nb, acc);

  const int lane = t & 63, wave = t >> 6;
  const int quad = lane >> 4, l16 = lane & 15;
  const int wm = wave >> 2, wn = wave & 3;

  if (isY2) {
#pragma unroll
    for (int j = 0; j < 4; ++j) {
      const int gc = nb * 256 + (j >> 1) * 128 + wn * 32 + (j & 1) * 16 + l16;
      const float bvv = m2f[gc];
#pragma unroll
      for (int i = 0; i < 8; ++i) {
        const int gr = mb * 256 + (i >> 2) * 128 + wm * 64 + (i & 3) * 16 + quad * 4;
#pragma unroll
        for (int r = 0; r < 4; ++r)
          y2[(long)(gr + r) * 1024 + gc] = (__bf16)(acc[i][j][r] + bvv);
      }
    }
  } else {
    const int bb = (mb * 256) / S;
    const int s0 = mb * 256 - bb * S;
#pragma unroll
    for (int j = 0; j < 4; ++j) {
      const int gc = nb * 256 + (j >> 1) * 128 + wn * 32 + (j & 1) * 16 + l16;
      const float bv = bvo[gc];
#pragma unroll
      for (int i = 0; i < 8; ++i) {
        const int sr = s0 + (i >> 2) * 128 + wm * 64 + (i & 3) * 16 + quad * 4;
        bf16x4 o;
#pragma unroll
        for (int r = 0; r < 4; ++r) o[r] = (__bf16)(acc[i][j][r] + bv);
        *(bf16x4*)&Ut[((long)bb * D + gc) * S + sr] = o;
      }
    }
  }
}

// ---------------- scoresP: 144 triangular 256^2 tiles -----------------------
__global__ void __launch_bounds__(512, 2)
scoresP(const __bf16* __restrict__ xb, const __bf16* __restrict__ y2,
        const float* __restrict__ uvec, __bf16* __restrict__ P,
        float* __restrict__ lsum, int S, int KD) {
  const int id = blockIdx.x;
  const int b = id / 36;
  const int r = id - b * 36;
  int mb = 0;
  while ((mb + 1) * (mb + 2) / 2 <= r) ++mb;   // triangular row, mb 0..7
  const int nb = r - mb * (mb + 1) / 2;        // 0..mb

  floatx4 acc[8][4] = {};
  gemm_core8p(y2 + (long)b * S * KD, xb + (long)b * S * KD, KD, 16, mb, nb, acc);

  const int t = threadIdx.x;
  const int lane = t & 63, wave = t >> 6;
  const int quad = lane >> 4, l16 = lane & 15;
  const int wm = wave >> 2, wn = wave & 3;

  __bf16* C = P + (long)b * S * S;
  float* lrow = lsum + (long)b * S;
  const float sc = 0.03125f;  // 1/sqrt(1024)
#pragma unroll
  for (int i = 0; i < 8; ++i) {
#pragma unroll
    for (int r4 = 0; r4 < 4; ++r4) {
      const int row = mb * 256 + (i >> 2) * 128 + wm * 64 + (i & 3) * 16 + quad * 4 + r4;
      const float urow = uvec[(long)b * S + row];
      float psum = 0.f;
#pragma unroll
      for (int j = 0; j < 4; ++j) {
        const int col = nb * 256 + (j >> 1) * 128 + wn * 32 + (j & 1) * 16 + l16;
        const float p =
            (col <= row) ? __expf(fabsf(acc[i][j][r4] + urow) * sc) : 0.f;
        psum += p;
        C[(long)row * S + col] = (__bf16)p;
      }
      psum += __shfl_xor(psum, 1, 64);
      psum += __shfl_xor(psum, 2, 64);
      psum += __shfl_xor(psum, 4, 64);
      psum += __shfl_xor(psum, 8, 64);
      if (l16 == 0) atomicAdd(&lrow[row], psum);
    }
  }
}

// ---------------- pvo: out = (P@U)/l + bo, causal-K -------------------------
__global__ void __launch_bounds__(512, 2)
gemm_pvo(const __bf16* __restrict__ P, const __bf16* __restrict__ Ut,
         const float* __restrict__ lsum, const float* __restrict__ bo,
         float* __restrict__ out, int S, int D) {
  const int id = blockIdx.x;          // 128 = 4 batches x 8 mb x 4 nb
  const int b = id >> 5;
  const int idx = id & 31;
  const int mb = idx >> 2;            // 0..7
  const int nb = idx & 3;             // 0..3

  floatx4 acc[8][4] = {};
  // causal K-extent: (mb+1)*256 elements = 4*(mb+1) K64-tiles (R6 BUG2 fix)
  gemm_core8p(P + (long)b * S * S, Ut + (long)b * D * S, S, 4 * (mb + 1), mb,
              nb, acc);

  const int t = threadIdx.x;
  const int lane = t & 63, wave = t >> 6;
  const int quad = lane >> 4, l16 = lane & 15;
  const int wm = wave >> 2, wn = wave & 3;
  const float* lrow = lsum + (long)b * S;

#pragma unroll
  for (int i = 0; i < 8; ++i) {
#pragma unroll
    for (int r = 0; r < 4; ++r) {
      const int row = mb * 256 + (i >> 2) * 128 + wm * 64 + (i & 3) * 16 + quad * 4 + r;
      const float inv = 1.f / lrow[row];
#pragma unroll
      for (int j = 0; j < 4; ++j) {
        const int col = nb * 256 + (j >> 1) * 128 + wn * 32 + (j & 1) * 16 + l16;
        out[((long)b * S + row) * D + col] = acc[i][j][r] * inv + bo[col];
      }
    }
  }
}

extern "C" void kernel_launch(void* const* d_in, const int* in_sizes, int n_in,
                              void* d_out, int out_size, void* d_ws, size_t ws_size,
                              hipStream_t stream) {
  const float* x = (const float*)d_in[0];
  const float* Wq = (const float*)d_in[1];
  const float* bq = (const float*)d_in[2];
  const float* Wk = (const float*)d_in[3];
  const float* bk = (const float*)d_in[4];
  const float* Wv = (const float*)d_in[5];
  const float* bv = (const float*)d_in[6];
  const float* Wo = (const float*)d_in[7];
  const float* bo = (const float*)d_in[8];
  float* out = (float*)d_out;

  constexpr int B = 4, S = 2048, D = 1024, KD = 1024;
  constexpr long MB_ = 1024 * 1024;

  char* w = (char*)d_ws;
  __bf16* xb  = (__bf16*)(w);              // 16 MB
  __bf16* y2  = (__bf16*)(w + 16 * MB_);   // 16 MB
  __bf16* Ut  = (__bf16*)(w + 32 * MB_);   // 16 MB
  __bf16* P   = (__bf16*)(w + 48 * MB_);   // 32 MB
  __bf16* Wob = (__bf16*)(w + 80 * MB_);   // 2 MB
  __bf16* Wqt = (__bf16*)(w + 82 * MB_);   // 2 MB
  __bf16* Wkt = (__bf16*)(w + 84 * MB_);   // 2 MB
  __bf16* Wvt = (__bf16*)(w + 86 * MB_);   // 2 MB
  __bf16* Mt  = (__bf16*)(w + 88 * MB_);   // 2 MB
  __bf16* Wvo = (__bf16*)(w + 90 * MB_);   // 2 MB
  float* lsum  = (float*)(w + 92 * MB_);             // 32 KB
  float* uvec  = (float*)(w + 92 * MB_ + 32768);     // 32 KB
  float* bvo   = (float*)(w + 92 * MB_ + 65536);     // 4 KB
  float* m2f   = (float*)(w + 92 * MB_ + 69632);     // 4 KB
  float* m1f   = (float*)(w + 92 * MB_ + 73728);     // 4 KB
  float* cscal = (float*)(w + 92 * MB_ + 77824);     // 4 B

  Ptr3 tp{{Wq, Wk, Wv}};
  prep2b<<<11010, 256, 0, stream>>>(Wo, tp, bv, bq, bk, x, Wob, Wqt, Wkt,
                                    Wvt, xb, bvo, cscal, lsum);

  gemmW<<<64, 512, 0, stream>>>(Wkt, Wqt, Wob, Wvt, Mt, Wvo, bk, bq, m1f, m2f);

  big1<<<384, 512, 0, stream>>>(xb, Mt, Wvo, m2f, bvo, y2, Ut, m1f, cscal,
                                uvec, S, D);

  scoresP<<<144, 512, 0, stream>>>(xb, y2, uvec, P, lsum, S, KD);

  gemm_pvo<<<128, 512, 0, stream>>>(P, Ut, lsum, bo, out, S, D);
}

// Round 8
// 253.292 us; speedup vs baseline: 1.0623x; 1.0623x over previous
//
#include <hip/hip_runtime.h>
#include <hip/hip_bf16.h>
#include <cstdint>

// ---------------------------------------------------------------------------
// SingleHeadAttentionLayer: B=4, S=2048, D=KD=VD=1024, fp32 in/out.
// Round 16: shape fixes around the FROZEN verified 8-phase 256^2 core.
// R7 counters: core delivers 4.78 TF/CU (49% per-CU peak) but dispatches
// are fill/chain-bound: gemmW 30us serial on 64/256 CUs; pvo mb=7 has an
// unsplittable 32-K-tile chain (56us).
// Changes (core + big1 + scoresP untouched):
//  1. pvoS: selective split-K: mb>=4 tiles split into 2 K-halves via pure
//     pointer offset (nT halves 10/12/14/16, even). 192 blocks, max chain
//     16 tiles. fp32 partials (32MB) reuse xb+y2 region (dead after
//     scoresP); every partial slot fully written -> no zero-init.
//     combineH: out = (p0+p1)/l + bo for heavy rows (4096 blk).
//  2. gemmWX: gemmW's GEMM/GEMV blocks merged with the x cast (4096 cast
//     blocks @512) so casts fill the 224 idle CUs (R5's hiding trick).
//     prepW keeps weights-only prep.
// Pipeline: prepW(2818@256) -> gemmWX(4160@512) -> big1(384@512)
//           -> scoresP(144@512) -> pvoS(192@512) -> combineH(4096@256)
// ---------------------------------------------------------------------------

typedef __attribute__((ext_vector_type(8))) __bf16 bf16x8;
typedef __attribute__((ext_vector_type(4))) __bf16 bf16x4;
typedef __attribute__((ext_vector_type(4))) float floatx4;

struct Ptr3 { const float* p[3]; };

__device__ __forceinline__ void async_copy16(const __bf16* g, const __bf16* l) {
  __builtin_amdgcn_global_load_lds(
      (const __attribute__((address_space(1))) unsigned int*)(const void*)g,
      (__attribute__((address_space(3))) unsigned int*)(unsigned)(uintptr_t)(const void*)l,
      16, 0, 0);
}

// ---------------- 8-phase 256x256 core, K-tiles of 64, nT EVEN --------------
// FROZEN (R7-verified). ONE call site per kernel (128 KB LDS). 512 threads.
__device__ __forceinline__ void gemm_core8p(const __bf16* __restrict__ pA,
                                            const __bf16* __restrict__ pB,
                                            int K, int nT, int mb, int nb,
                                            floatx4 (&acc)[8][4]) {
  __shared__ __align__(16) __bf16 As[2][16384];
  __shared__ __align__(16) __bf16 Bs[2][16384];

  const int t = threadIdx.x;           // 0..511
  const int lane = t & 63;
  const int wave = t >> 6;             // 0..7
  const int quad = lane >> 4;          // 0..3
  const int l16 = lane & 15;
  const int wm = wave >> 2;            // 0..1 -> row strip wm*64 in each half
  const int wn = wave & 3;             // 0..3 -> col strip wn*32 in each half

  const int r0 = t >> 3;
  const int csw = ((t & 7) ^ (r0 & 7)) * 8;
  const __bf16* gA = pA + (long)(mb * 256 + r0) * K + csw;
  const __bf16* gB = pB + (long)(nb * 256 + r0) * K + csw;
  const long row64 = (long)64 * K;
  const long row128 = (long)128 * K;

  auto stageA = [&](int kt, int half) {
    const long ko = (long)kt * 64 + (long)half * row128;
    __bf16* d = &As[kt & 1][half * 8192 + t * 8];
    async_copy16(gA + ko, d);
    async_copy16(gA + ko + row64, d + 4096);
  };
  auto stageB = [&](int kt, int half) {
    const long ko = (long)kt * 64 + (long)half * row128;
    __bf16* d = &Bs[kt & 1][half * 8192 + t * 8];
    async_copy16(gB + ko, d);
    async_copy16(gB + ko + row64, d + 4096);
  };
  auto cl = [&](int kt) { return kt < nT ? kt : nT - 1; };

  bf16x8 af[4][2], bfr[2][2];
  auto ldsA = [&](int buf, int ihalf) {
#pragma unroll
    for (int i2 = 0; i2 < 4; ++i2) {
      const int rl = wm * 64 + i2 * 16 + l16;
      const int rb = ihalf * 8192 + rl * 64;
      const int key = rl & 7;
#pragma unroll
      for (int ks = 0; ks < 2; ++ks)
        af[i2][ks] = *(const bf16x8*)&As[buf][rb + (((ks * 4 + quad) ^ key) << 3)];
    }
  };
  auto ldsB = [&](int buf, int jhalf) {
#pragma unroll
    for (int j2 = 0; j2 < 2; ++j2) {
      const int rl = wn * 32 + j2 * 16 + l16;
      const int rb = jhalf * 8192 + rl * 64;
      const int key = rl & 7;
#pragma unroll
      for (int ks = 0; ks < 2; ++ks)
        bfr[j2][ks] = *(const bf16x8*)&Bs[buf][rb + (((ks * 4 + quad) ^ key) << 3)];
    }
  };
  auto mfmaQ = [&](int ihalf, int jhalf) {
    __builtin_amdgcn_s_setprio(1);
#pragma unroll
    for (int ks = 0; ks < 2; ++ks)
#pragma unroll
      for (int i2 = 0; i2 < 4; ++i2)
#pragma unroll
        for (int j2 = 0; j2 < 2; ++j2)
          acc[ihalf * 4 + i2][jhalf * 2 + j2] =
              __builtin_amdgcn_mfma_f32_16x16x32_bf16(
                  af[i2][ks], bfr[j2][ks],
                  acc[ihalf * 4 + i2][jhalf * 2 + j2], 0, 0, 0);
    __builtin_amdgcn_s_setprio(0);
  };

#define VM6 asm volatile("s_waitcnt vmcnt(6)" ::: "memory")
#define PHASE(LDSOP, STAGEOP, WAITOP, IH, JH)                 \
  LDSOP;                                                      \
  STAGEOP;                                                    \
  WAITOP;                                                     \
  __builtin_amdgcn_sched_barrier(0);                          \
  __builtin_amdgcn_s_barrier();                               \
  asm volatile("s_waitcnt lgkmcnt(0)" ::: "memory");          \
  __builtin_amdgcn_sched_barrier(0);                          \
  mfmaQ(IH, JH);                                              \
  __builtin_amdgcn_s_barrier();

  stageA(0, 0); stageB(0, 0); stageB(0, 1); stageA(0, 1);
  stageA(1, 0); stageB(1, 1); stageA(1, 1);
  VM6;
  __builtin_amdgcn_s_barrier();
  __builtin_amdgcn_sched_barrier(0);

  const int nIter = nT >> 1;
  for (int it = 0, T = 0; it < nIter; ++it, T += 2) {
    PHASE((ldsA(0, 0), ldsB(0, 0)), stageB(cl(T + 1), 0), (void)0, 0, 0)
    PHASE(ldsB(0, 1),               stageA(cl(T + 2), 0), (void)0, 0, 1)
    PHASE(ldsA(0, 1),               stageB(cl(T + 2), 1), (void)0, 1, 1)
    PHASE(ldsB(0, 0),               stageA(cl(T + 2), 1), VM6,     1, 0)
    PHASE((ldsA(1, 0), ldsB(1, 0)), stageB(cl(T + 2), 0), (void)0, 0, 0)
    PHASE(ldsB(1, 1),               stageA(cl(T + 3), 0), (void)0, 0, 1)
    PHASE(ldsA(1, 1),               stageB(cl(T + 3), 1), (void)0, 1, 1)
    PHASE(ldsB(1, 0),               stageA(cl(T + 3), 1), VM6,     1, 0)
  }
  __syncthreads();
#undef PHASE
#undef VM6
}

// Epilogue maps: row(i,r) = (i>>2)*128 + wm*64 + (i&3)*16 + quad*4 + r
//                col(j)   = (j>>1)*128 + wn*32 + (j&1)*16 + l16

// ---------------- prepW: weight-side prep (no x cast) -----------------------
__global__ void prepW(const float* __restrict__ Wo, Ptr3 tp,
                      const float* __restrict__ bv, const float* __restrict__ bq,
                      const float* __restrict__ bk,
                      __bf16* __restrict__ Wob, __bf16* __restrict__ Wqt,
                      __bf16* __restrict__ Wkt, __bf16* __restrict__ Wvt,
                      float* __restrict__ bvo, float* __restrict__ cscal,
                      float* __restrict__ lsum) {
  __shared__ __bf16 tile[64][66];
  __shared__ float wsum[4];
  const int bid = blockIdx.x;
  const int t = threadIdx.x;
  if (bid < 1024) {  // Wo cast
    const long e = ((long)bid * 256 + t) * 4;
    const float4 f = *(const float4*)(Wo + e);
    bf16x4 o;
    o[0] = (__bf16)f.x; o[1] = (__bf16)f.y; o[2] = (__bf16)f.z; o[3] = (__bf16)f.w;
    *(bf16x4*)(Wob + e) = o;
  } else if (bid < 1792) {  // transposed casts
    const int seg = (bid - 1024) >> 8;
    const int idx = (bid - 1024) & 255;
    const float* src = tp.p[seg];
    __bf16* dstw = seg == 0 ? Wqt : (seg == 1 ? Wkt : Wvt);
    const int r0 = (idx >> 4) * 64, c0 = (idx & 15) * 64;
#pragma unroll
    for (int e = 0; e < 16; ++e) {
      const int i = e * 256 + t;
      const int r = i >> 6, c = i & 63;
      tile[r][c] = (__bf16)src[(long)(r0 + r) * 1024 + (c0 + c)];
    }
    __syncthreads();
#pragma unroll
    for (int e = 0; e < 16; ++e) {
      const int i = e * 256 + t;
      const int r = i >> 6, c = i & 63;
      dstw[(long)(c0 + r) * 1024 + (r0 + c)] = tile[c][r];
    }
  } else if (bid < 2816) {  // bvo
    const int d = bid - 1792;
    const float* row = Wo + (long)d * 1024;
    float s = 0.f;
    for (int v = t; v < 1024; v += 256) s += bv[v] * row[v];
#pragma unroll
    for (int off = 32; off > 0; off >>= 1) s += __shfl_down(s, off, 64);
    if ((t & 63) == 0) wsum[t >> 6] = s;
    __syncthreads();
    if (t == 0) bvo[d] = wsum[0] + wsum[1] + wsum[2] + wsum[3];
  } else if (bid == 2816) {  // c = bq . bk
    float s = 0.f;
    for (int i = t; i < 1024; i += 256) s += bq[i] * bk[i];
#pragma unroll
    for (int off = 32; off > 0; off >>= 1) s += __shfl_down(s, off, 64);
    if ((t & 63) == 0) wsum[t >> 6] = s;
    __syncthreads();
    if (t == 0) *cscal = wsum[0] + wsum[1] + wsum[2] + wsum[3];
  } else {  // zero lsum
#pragma unroll
    for (int e = 0; e < 8; ++e)
      *(float4*)(lsum + (e * 256 + t) * 4) = float4{0.f, 0.f, 0.f, 0.f};
  }
}

// ---------------- gemmWX: Mt(16)+Wvo(16)@256^2 + GEMVs(32) + x cast(4096) ---
__global__ void __launch_bounds__(512, 2)
gemmWX(const __bf16* __restrict__ Wkt, const __bf16* __restrict__ Wqt,
       const __bf16* __restrict__ Wob, const __bf16* __restrict__ Wvt,
       __bf16* __restrict__ Mt, __bf16* __restrict__ Wvo,
       const float* __restrict__ bk, const float* __restrict__ bq,
       float* __restrict__ m1f, float* __restrict__ m2f,
       const float* __restrict__ x, __bf16* __restrict__ xb) {
  const int id = blockIdx.x;
  const int t = threadIdx.x;

  if (id >= 64) {  // x cast: 4096 blocks x 512 thr x 4 f32
    const long i = ((long)(id - 64) * 512 + t) * 4;
    const float4 f = *(const float4*)(x + i);
    bf16x4 o;
    o[0] = (__bf16)f.x; o[1] = (__bf16)f.y; o[2] = (__bf16)f.z; o[3] = (__bf16)f.w;
    *(bf16x4*)(xb + i) = o;
    return;
  }
  if (id >= 32) {  // m1[row]=Wqt[row,:].bk / m2[row]=Wkt[row,:].bq
    const int g = id - 32;
    const bool isM2 = g >= 16;
    const int q = g & 15;
    const __bf16* Wt = isM2 ? Wkt : Wqt;
    const float* bvec = isM2 ? bq : bk;
    float* dst = isM2 ? m2f : m1f;
    const int row = q * 64 + (t >> 3);
    const int l8 = t & 7;
    const __bf16* wr = Wt + (long)row * 1024 + l8 * 128;
    const float* bp = bvec + l8 * 128;
    float s = 0.f;
#pragma unroll
    for (int jj = 0; jj < 16; ++jj) {
      bf16x8 wv = *(const bf16x8*)(wr + jj * 8);
#pragma unroll
      for (int e = 0; e < 8; ++e) s += (float)wv[e] * bp[jj * 8 + e];
    }
    s += __shfl_xor(s, 1, 64);
    s += __shfl_xor(s, 2, 64);
    s += __shfl_xor(s, 4, 64);
    if (l8 == 0) dst[row] = s;
    return;
  }

  const bool isMt = id < 16;
  const int w = isMt ? id : id - 16;
  const int mb = w >> 2, nb = w & 3;
  const __bf16* pA = isMt ? Wkt : Wob;
  const __bf16* pB = isMt ? Wqt : Wvt;
  __bf16* dst = isMt ? Mt : Wvo;

  floatx4 acc[8][4] = {};
  gemm_core8p(pA, pB, 1024, 16, mb, nb, acc);

  const int lane = t & 63, wave = t >> 6;
  const int quad = lane >> 4, l16 = lane & 15;
  const int wm = wave >> 2, wn = wave & 3;
#pragma unroll
  for (int j = 0; j < 4; ++j) {
    const int gc = nb * 256 + (j >> 1) * 128 + wn * 32 + (j & 1) * 16 + l16;
#pragma unroll
    for (int i = 0; i < 8; ++i) {
      const int gr = mb * 256 + (i >> 2) * 128 + wm * 64 + (i & 3) * 16 + quad * 4;
#pragma unroll
      for (int r = 0; r < 4; ++r)
        dst[(long)(gr + r) * 1024 + gc] = (__bf16)acc[i][j][r];
    }
  }
}

// ---------------- big1: y2(128) + Ut(128) @256^2 + u GEMV(128) --------------
__global__ void __launch_bounds__(512, 2)
big1(const __bf16* __restrict__ xb, const __bf16* __restrict__ Mt,
     const __bf16* __restrict__ Wvo, const float* __restrict__ m2f,
     const float* __restrict__ bvo, __bf16* __restrict__ y2,
     __bf16* __restrict__ Ut, const float* __restrict__ m1f,
     const float* __restrict__ cscal, float* __restrict__ uvec,
     int S, int D) {
  const int id = blockIdx.x;
  const int t = threadIdx.x;

  if (id >= 256) {  // u rows
    const int k = id - 256;
    const int row = k * 64 + (t >> 3);
    const int l8 = t & 7;
    const float c = *cscal;
    const __bf16* xr = xb + (long)row * 1024 + l8 * 128;
    const float* mp = m1f + l8 * 128;
    float s = 0.f;
#pragma unroll
    for (int jj = 0; jj < 16; ++jj) {
      bf16x8 xv = *(const bf16x8*)(xr + jj * 8);
#pragma unroll
      for (int e = 0; e < 8; ++e) s += (float)xv[e] * mp[jj * 8 + e];
    }
    s += __shfl_xor(s, 1, 64);
    s += __shfl_xor(s, 2, 64);
    s += __shfl_xor(s, 4, 64);
    if (l8 == 0) uvec[row] = s + c;
    return;
  }

  const bool isY2 = id < 128;
  const int w = isY2 ? id : id - 128;
  const int mb = w >> 2;
  const int nb = w & 3;
  const __bf16* pB = isY2 ? Mt : Wvo;

  floatx4 acc[8][4] = {};
  gemm_core8p(xb, pB, 1024, 16, mb, nb, acc);

  const int lane = t & 63, wave = t >> 6;
  const int quad = lane >> 4, l16 = lane & 15;
  const int wm = wave >> 2, wn = wave & 3;

  if (isY2) {
#pragma unroll
    for (int j = 0; j < 4; ++j) {
      const int gc = nb * 256 + (j >> 1) * 128 + wn * 32 + (j & 1) * 16 + l16;
      const float bvv = m2f[gc];
#pragma unroll
      for (int i = 0; i < 8; ++i) {
        const int gr = mb * 256 + (i >> 2) * 128 + wm * 64 + (i & 3) * 16 + quad * 4;
#pragma unroll
        for (int r = 0; r < 4; ++r)
          y2[(long)(gr + r) * 1024 + gc] = (__bf16)(acc[i][j][r] + bvv);
      }
    }
  } else {
    const int bb = (mb * 256) / S;
    const int s0 = mb * 256 - bb * S;
#pragma unroll
    for (int j = 0; j < 4; ++j) {
      const int gc = nb * 256 + (j >> 1) * 128 + wn * 32 + (j & 1) * 16 + l16;
      const float bv = bvo[gc];
#pragma unroll
      for (int i = 0; i < 8; ++i) {
        const int sr = s0 + (i >> 2) * 128 + wm * 64 + (i & 3) * 16 + quad * 4;
        bf16x4 o;
#pragma unroll
        for (int r = 0; r < 4; ++r) o[r] = (__bf16)(acc[i][j][r] + bv);
        *(bf16x4*)&Ut[((long)bb * D + gc) * S + sr] = o;
      }
    }
  }
}

// ---------------- scoresP: 144 triangular 256^2 tiles -----------------------
__global__ void __launch_bounds__(512, 2)
scoresP(const __bf16* __restrict__ xb, const __bf16* __restrict__ y2,
        const float* __restrict__ uvec, __bf16* __restrict__ P,
        float* __restrict__ lsum, int S, int KD) {
  const int id = blockIdx.x;
  const int b = id / 36;
  const int r = id - b * 36;
  int mb = 0;
  while ((mb + 1) * (mb + 2) / 2 <= r) ++mb;
  const int nb = r - mb * (mb + 1) / 2;

  floatx4 acc[8][4] = {};
  gemm_core8p(y2 + (long)b * S * KD, xb + (long)b * S * KD, KD, 16, mb, nb, acc);

  const int t = threadIdx.x;
  const int lane = t & 63, wave = t >> 6;
  const int quad = lane >> 4, l16 = lane & 15;
  const int wm = wave >> 2, wn = wave & 3;

  __bf16* C = P + (long)b * S * S;
  float* lrow = lsum + (long)b * S;
  const float sc = 0.03125f;
#pragma unroll
  for (int i = 0; i < 8; ++i) {
#pragma unroll
    for (int r4 = 0; r4 < 4; ++r4) {
      const int row = mb * 256 + (i >> 2) * 128 + wm * 64 + (i & 3) * 16 + quad * 4 + r4;
      const float urow = uvec[(long)b * S + row];
      float psum = 0.f;
#pragma unroll
      for (int j = 0; j < 4; ++j) {
        const int col = nb * 256 + (j >> 1) * 128 + wn * 32 + (j & 1) * 16 + l16;
        const float p =
            (col <= row) ? __expf(fabsf(acc[i][j][r4] + urow) * sc) : 0.f;
        psum += p;
        C[(long)row * S + col] = (__bf16)p;
      }
      psum += __shfl_xor(psum, 1, 64);
      psum += __shfl_xor(psum, 2, 64);
      psum += __shfl_xor(psum, 4, 64);
      psum += __shfl_xor(psum, 8, 64);
      if (l16 == 0) atomicAdd(&lrow[row], psum);
    }
  }
}

// ---------------- pvoS: split-K pvo (192 blk) -------------------------------
// id<128: HEAVY (b, mb=4..7, nb, khalf): half chain nT=2(mb+1), fp32 partial
//   part[b][mb-4][khalf][256][1024] (K-offset = pure pointer offset into P,Ut).
// id>=128: LIGHT (b, mb=0..3, nb): full chain nT=4(mb+1), direct out.
__global__ void __launch_bounds__(512, 2)
pvoS(const __bf16* __restrict__ P, const __bf16* __restrict__ Ut,
     const float* __restrict__ lsum, const float* __restrict__ bo,
     float* __restrict__ out, float* __restrict__ part, int S, int D) {
  const int id = blockIdx.x;
  const int t = threadIdx.x;

  const __bf16 *pA, *pB;
  int nT, mb, nb, b, khalf = 0;
  bool heavy;
  if (id < 128) {
    heavy = true;
    khalf = id & 1;
    const int rest = id >> 1;
    nb = rest & 3;
    const int mbh = (rest >> 2) & 3;
    b = rest >> 4;
    mb = 4 + mbh;
    nT = 2 * (mb + 1);                      // 10/12/14/16, even
    const long koff = (long)khalf * nT * 64;  // K-elem offset
    pA = P + (long)b * S * S + koff;
    pB = Ut + (long)b * D * S + koff;
  } else {
    heavy = false;
    const int l = id - 128;
    nb = l & 3;
    mb = (l >> 2) & 3;
    b = l >> 4;
    nT = 4 * (mb + 1);                      // 4/8/12/16, even
    pA = P + (long)b * S * S;
    pB = Ut + (long)b * D * S;
  }

  floatx4 acc[8][4] = {};
  gemm_core8p(pA, pB, S, nT, mb, nb, acc);

  const int lane = t & 63, wave = t >> 6;
  const int quad = lane >> 4, l16 = lane & 15;
  const int wm = wave >> 2, wn = wave & 3;

  if (heavy) {
    float* ps = part + ((long)((b * 4 + (mb - 4)) * 2 + khalf)) * 256 * 1024;
#pragma unroll
    for (int i = 0; i < 8; ++i) {
#pragma unroll
      for (int r = 0; r < 4; ++r) {
        const int lr = (i >> 2) * 128 + wm * 64 + (i & 3) * 16 + quad * 4 + r;
#pragma unroll
        for (int j = 0; j < 4; ++j) {
          const int col = nb * 256 + (j >> 1) * 128 + wn * 32 + (j & 1) * 16 + l16;
          ps[(long)lr * 1024 + col] = acc[i][j][r];
        }
      }
    }
  } else {
    const float* lrow = lsum + (long)b * S;
#pragma unroll
    for (int i = 0; i < 8; ++i) {
#pragma unroll
      for (int r = 0; r < 4; ++r) {
        const int row = mb * 256 + (i >> 2) * 128 + wm * 64 + (i & 3) * 16 + quad * 4 + r;
        const float inv = 1.f / lrow[row];
#pragma unroll
        for (int j = 0; j < 4; ++j) {
          const int col = nb * 256 + (j >> 1) * 128 + wn * 32 + (j & 1) * 16 + l16;
          out[((long)b * S + row) * D + col] = acc[i][j][r] * inv + bo[col];
        }
      }
    }
  }
}

// ---------------- combineH: heavy rows out = (p0+p1)/l + bo -----------------
__global__ void combineH(const float* __restrict__ part,
                         const float* __restrict__ lsum,
                         const float* __restrict__ bo, float* __restrict__ out,
                         int S, int D) {
  const int hr = blockIdx.x;           // 0..4095 (b x 4 mbh x 256 rows)
  const int t = threadIdx.x;           // 256; col = t*4
  const int b = hr >> 10;
  const int lr = hr & 1023;
  const int mbh = lr >> 8;
  const int r256 = lr & 255;
  const int srow = (4 + mbh) * 256 + r256;
  const float inv = 1.f / lsum[(long)b * S + srow];
  const long base = (long)((b * 4 + mbh) * 2) * 256 * 1024 + (long)r256 * 1024;
  const float4 p0 = *(const float4*)(part + base + t * 4);
  const float4 p1 = *(const float4*)(part + base + 256 * 1024 + t * 4);
  const float4 bv = *(const float4*)(bo + t * 4);
  float4 o;
  o.x = (p0.x + p1.x) * inv + bv.x;
  o.y = (p0.y + p1.y) * inv + bv.y;
  o.z = (p0.z + p1.z) * inv + bv.z;
  o.w = (p0.w + p1.w) * inv + bv.w;
  *(float4*)(out + ((long)b * S + srow) * D + t * 4) = o;
}

extern "C" void kernel_launch(void* const* d_in, const int* in_sizes, int n_in,
                              void* d_out, int out_size, void* d_ws, size_t ws_size,
                              hipStream_t stream) {
  const float* x = (const float*)d_in[0];
  const float* Wq = (const float*)d_in[1];
  const float* bq = (const float*)d_in[2];
  const float* Wk = (const float*)d_in[3];
  const float* bk = (const float*)d_in[4];
  const float* Wv = (const float*)d_in[5];
  const float* bv = (const float*)d_in[6];
  const float* Wo = (const float*)d_in[7];
  const float* bo = (const float*)d_in[8];
  float* out = (float*)d_out;

  constexpr int B = 4, S = 2048, D = 1024, KD = 1024;
  constexpr long MB_ = 1024 * 1024;

  char* w = (char*)d_ws;
  __bf16* xb  = (__bf16*)(w);              // 16 MB  [dead after scoresP]
  __bf16* y2  = (__bf16*)(w + 16 * MB_);   // 16 MB  [dead after scoresP]
  __bf16* Ut  = (__bf16*)(w + 32 * MB_);   // 16 MB
  __bf16* P   = (__bf16*)(w + 48 * MB_);   // 32 MB
  __bf16* Wob = (__bf16*)(w + 80 * MB_);   // 2 MB
  __bf16* Wqt = (__bf16*)(w + 82 * MB_);   // 2 MB
  __bf16* Wkt = (__bf16*)(w + 84 * MB_);   // 2 MB
  __bf16* Wvt = (__bf16*)(w + 86 * MB_);   // 2 MB
  __bf16* Mt  = (__bf16*)(w + 88 * MB_);   // 2 MB
  __bf16* Wvo = (__bf16*)(w + 90 * MB_);   // 2 MB
  float* lsum  = (float*)(w + 92 * MB_);             // 32 KB
  float* uvec  = (float*)(w + 92 * MB_ + 32768);     // 32 KB
  float* bvo   = (float*)(w + 92 * MB_ + 65536);     // 4 KB
  float* m2f   = (float*)(w + 92 * MB_ + 69632);     // 4 KB
  float* m1f   = (float*)(w + 92 * MB_ + 73728);     // 4 KB
  float* cscal = (float*)(w + 92 * MB_ + 77824);     // 4 B
  float* part  = (float*)(w);              // 32 MB, aliases xb+y2 (dead)

  Ptr3 tp{{Wq, Wk, Wv}};
  prepW<<<2818, 256, 0, stream>>>(Wo, tp, bv, bq, bk, Wob, Wqt, Wkt, Wvt,
                                  bvo, cscal, lsum);

  gemmWX<<<4160, 512, 0, stream>>>(Wkt, Wqt, Wob, Wvt, Mt, Wvo, bk, bq,
                                   m1f, m2f, x, xb);

  big1<<<384, 512, 0, stream>>>(xb, Mt, Wvo, m2f, bvo, y2, Ut, m1f, cscal,
                                uvec, S, D);

  scoresP<<<144, 512, 0, stream>>>(xb, y2, uvec, P, lsum, S, KD);

  pvoS<<<192, 512, 0, stream>>>(P, Ut, lsum, bo, out, part, S, D);

  combineH<<<4096, 256, 0, stream>>>(part, lsum, bo, out, S, D);
}